// Round 2
// baseline (320.886 us; speedup 1.0000x reference)
//
#include <hip/hip_runtime.h>
#include <math.h>

#define BB 8
#define CC 1024
#define PP 4096   // H*W = 64*64
#define KK 16
#define EPSF 1e-8f

// ws layout:
//   num     [B][C][K]  @ 0          (512 KiB)   (k-contiguous)
//   den     [B][K]     @ 0x80000    (512 B)
//   pn      [B][K]     @ 0x80200    (512 B)
//   proto_t [B][C][K]  @ 0x100000   (512 KiB)

// ---- kernel 1: masked per-class channel sums (prototype numerators) ----
// grid 1024 = B(8) x cgroup(128); block 256 = 4 waves; wave handles 2 channels,
// lanes cover pixels via float4/int4 (1 KiB per wave-load). 16 waves/CU.
__global__ __launch_bounds__(256) void k_num(const float* __restrict__ sf,
                                             const int* __restrict__ sm,
                                             float* __restrict__ num) {
    int b    = blockIdx.x >> 7;
    int cg   = blockIdx.x & 127;
    int w    = threadIdx.x >> 6;
    int lane = threadIdx.x & 63;
    int c0   = cg * 8 + w * 2;

    const float4* f0 = (const float4*)(sf + ((size_t)b * CC + c0) * PP);
    const float4* f1 = (const float4*)(sf + ((size_t)b * CC + c0 + 1) * PP);
    const int4*   m4 = (const int4*)(sm + (size_t)b * PP);

    float a0[KK], a1[KK];
#pragma unroll
    for (int k = 0; k < KK; ++k) { a0[k] = 0.f; a1[k] = 0.f; }

    for (int it = 0; it < PP / 256; ++it) {
        int p = it * 64 + lane;
        int4   mv = m4[p];
        float4 v0 = f0[p];
        float4 v1 = f1[p];

        auto px = [&](int m_, float x0, float x1) {
#pragma unroll
            for (int k = 0; k < KK; ++k) {
                float pr = (m_ == k + 1) ? 1.0f : 0.0f;
                a0[k] = fmaf(pr, x0, a0[k]);
                a1[k] = fmaf(pr, x1, a1[k]);
            }
        };
        px(mv.x, v0.x, v1.x);
        px(mv.y, v0.y, v1.y);
        px(mv.z, v0.z, v1.z);
        px(mv.w, v0.w, v1.w);
    }

#pragma unroll
    for (int k = 0; k < KK; ++k) {
#pragma unroll
        for (int s = 32; s >= 1; s >>= 1) {
            a0[k] += __shfl_xor(a0[k], s, 64);
            a1[k] += __shfl_xor(a1[k], s, 64);
        }
    }

    if (lane == 0) {
        float4* o0 = (float4*)(num + ((size_t)b * CC + c0) * KK);
        float4* o1 = (float4*)(num + ((size_t)b * CC + c0 + 1) * KK);
#pragma unroll
        for (int g = 0; g < 4; ++g) {
            o0[g] = make_float4(a0[4*g], a0[4*g+1], a0[4*g+2], a0[4*g+3]);
            o1[g] = make_float4(a1[4*g], a1[4*g+1], a1[4*g+2], a1[4*g+3]);
        }
    }
}

// ---- kernel 2: per-class pixel counts (denominators) ----
__global__ __launch_bounds__(256) void k_den(const int* __restrict__ sm,
                                             float* __restrict__ den) {
    int b    = blockIdx.x;
    int tid  = threadIdx.x;
    int wave = tid >> 6;
    int lane = tid & 63;
    const int* m = sm + (size_t)b * PP;

    float cnt[KK];
#pragma unroll
    for (int k = 0; k < KK; ++k) cnt[k] = 0.f;

    for (int it = 0; it < PP / 256; ++it) {
        int mv = m[it * 256 + tid];
#pragma unroll
        for (int k = 0; k < KK; ++k) cnt[k] += (mv == k + 1) ? 1.0f : 0.0f;
    }

#pragma unroll
    for (int k = 0; k < KK; ++k) {
#pragma unroll
        for (int s = 32; s >= 1; s >>= 1) cnt[k] += __shfl_xor(cnt[k], s, 64);
    }

    __shared__ float wsum[4][KK];
    if (lane == 0) {
#pragma unroll
        for (int k = 0; k < KK; ++k) wsum[wave][k] = cnt[k];
    }
    __syncthreads();
    if (tid < KK)
        den[b * KK + tid] = wsum[0][tid] + wsum[1][tid] + wsum[2][tid] + wsum[3][tid];
}

// ---- kernel 3: prototypes (num/den) in [b][c][k] layout, plus norms ----
// grid 8 (one per batch); thread t -> (k = t&15, c-stride 16). Fully coalesced.
__global__ __launch_bounds__(256) void k_proto(const float* __restrict__ num,
                                               const float* __restrict__ den,
                                               float* __restrict__ proto_t,
                                               float* __restrict__ pn) {
    int b   = blockIdx.x;
    int tid = threadIdx.x;
    int k   = tid & 15;
    int cs  = tid >> 4;   // 0..15
    float d = den[b * KK + k];

    float sq = 0.f;
    for (int c = cs; c < CC; c += 16) {
        size_t idx = ((size_t)b * CC + c) * KK + k;
        float pv = num[idx] / d;          // IEEE div, matches numpy
        proto_t[idx] = pv;
        sq = fmaf(pv, pv, sq);
    }

    // within wave: lanes sharing k differ in bits 4,5 of tid
    sq += __shfl_xor(sq, 16, 64);
    sq += __shfl_xor(sq, 32, 64);
    __shared__ float red[4][KK];
    if ((tid & 63) < KK) red[tid >> 6][k] = sq;
    __syncthreads();
    if (tid < KK)
        pn[b * KK + tid] = sqrtf(red[0][tid] + red[1][tid] + red[2][tid] + red[3][tid]);
}

// ---- kernel 4: cosine similarity + argmax ----
// grid 256 = B(8) x pgroup(32); block 512 = 8 waves, wave = one 128-channel
// chunk x 128 pixels (float2/lane). Protos via wave-uniform scalar loads.
// Cross-chunk reduce: conflict-free float2 LDS (k-major, b64 writes).
__global__ __launch_bounds__(512) void k_match(const float* __restrict__ qf,
                                               const float* __restrict__ proto_t,
                                               const float* __restrict__ pn,
                                               int* __restrict__ out) {
    int b    = blockIdx.x >> 5;
    int pg   = blockIdx.x & 31;
    int tid  = threadIdx.x;
    int lane = tid & 63;
    int w    = __builtin_amdgcn_readfirstlane(tid >> 6);  // 0..7, wave-uniform
    int c0   = w * 128;
    int px0  = pg * 128;

    const float2* q2 = (const float2*)(qf + ((size_t)b * CC + c0) * PP + px0);
    const float*  pt = proto_t + ((size_t)b * CC + c0) * KK;

    float2 dot[KK];
#pragma unroll
    for (int k = 0; k < KK; ++k) { dot[k].x = 0.f; dot[k].y = 0.f; }
    float2 qs; qs.x = 0.f; qs.y = 0.f;

    for (int ci = 0; ci < 128; ++ci) {
        float2 qv = q2[(size_t)ci * (PP / 2) + lane];
        const float* pr = pt + ci * KK;
#pragma unroll
        for (int k = 0; k < KK; ++k) {
            float p = pr[k];
            dot[k].x = fmaf(p, qv.x, dot[k].x);
            dot[k].y = fmaf(p, qv.y, dot[k].y);
        }
        qs.x = fmaf(qv.x, qv.x, qs.x);
        qs.y = fmaf(qv.y, qv.y, qs.y);
    }

    // buf[c][k][lane] as float2: lanes stride 8B -> conflict-free b64 LDS ops
    __shared__ float2 buf[4][KK + 1][64];   // 34.8 KiB

    if (w >= 4) {
#pragma unroll
        for (int k = 0; k < KK; ++k) buf[w - 4][k][lane] = dot[k];
        buf[w - 4][KK][lane] = qs;
    }
    __syncthreads();
    if (w < 4) {
#pragma unroll
        for (int k = 0; k < KK; ++k) {
            float2 t = buf[w][k][lane];
            t.x += dot[k].x; t.y += dot[k].y;
            buf[w][k][lane] = t;
        }
        float2 t = buf[w][KK][lane];
        t.x += qs.x; t.y += qs.y;
        buf[w][KK][lane] = t;
    }
    __syncthreads();

    if (tid < 128) {
        int px = tid;                      // pixel px0+px; buf[c][k] viewed as float[128]
        const float* bf = (const float*)buf;
        float q2s = 0.f;
#pragma unroll
        for (int c = 0; c < 4; ++c) q2s += bf[((c * (KK + 1)) + KK) * 128 + px];
        float qn = sqrtf(q2s);

        float bv = -INFINITY;
        int   bi = 0;
#pragma unroll
        for (int k = 0; k < KK; ++k) {
            float dk = 0.f;
#pragma unroll
            for (int c = 0; c < 4; ++c) dk += bf[((c * (KK + 1)) + k) * 128 + px];
            float s = dk / fmaxf(pn[b * KK + k] * qn, EPSF);
            if (s > bv) { bv = s; bi = k; }   // strict '>' = first-max (jnp.argmax)
        }
        out[(size_t)b * PP + px0 + px] = bi;
    }
}

extern "C" void kernel_launch(void* const* d_in, const int* in_sizes, int n_in,
                              void* d_out, int out_size, void* d_ws, size_t ws_size,
                              hipStream_t stream) {
    const float* sf = (const float*)d_in[0];  // support_features (8,1024,64,64) f32
    const int*   sm = (const int*)d_in[1];    // support_masks    (8,1,64,64)    i32
    const float* qf = (const float*)d_in[2];  // query_features   (8,1024,64,64) f32
    int* out = (int*)d_out;                   // (8,64,64) i32

    char*  ws      = (char*)d_ws;
    float* num     = (float*)(ws);
    float* den     = (float*)(ws + (512u << 10));
    float* pn      = (float*)(ws + (512u << 10) + 512);
    float* proto_t = (float*)(ws + (1u << 20));

    hipLaunchKernelGGL(k_num,   dim3(1024), dim3(256), 0, stream, sf, sm, num);
    hipLaunchKernelGGL(k_den,   dim3(8),    dim3(256), 0, stream, sm, den);
    hipLaunchKernelGGL(k_proto, dim3(8),    dim3(256), 0, stream, num, den, proto_t, pn);
    hipLaunchKernelGGL(k_match, dim3(256),  dim3(512), 0, stream, qf, proto_t, pn, out);
}

// Round 3
// 298.607 us; speedup vs baseline: 1.0746x; 1.0746x over previous
//
#include <hip/hip_runtime.h>
#include <math.h>

#define BB 8
#define CC 1024
#define PP 4096   // H*W = 64*64
#define KK 16
#define EPSF 1e-8f

// ws layout:
//   num     [B][K][C]  @ 0          (512 KiB)   (c-contiguous)
//   pn      [B][K]     @ 0x80000    (512 B)
//   proto_t [B][C][K]  @ 0x100000   (512 KiB)   (k-contiguous for k_match)

// ---- kernel 1: masked per-class channel sums (prototype numerators) ----
// grid 1024 = B(8) x cgroup(128); block 256 = 4 waves; wave handles 2 channels,
// lanes cover pixels via float4/int4 (1 KiB per wave-load). 4 blocks/CU.
__global__ __launch_bounds__(256) void k_num(const float* __restrict__ sf,
                                             const int* __restrict__ sm,
                                             float* __restrict__ num) {
    int b    = blockIdx.x >> 7;
    int cg   = blockIdx.x & 127;
    int w    = threadIdx.x >> 6;
    int lane = threadIdx.x & 63;
    int c0   = cg * 8 + w * 2;

    const float4* f0 = (const float4*)(sf + ((size_t)b * CC + c0) * PP);
    const float4* f1 = (const float4*)(sf + ((size_t)b * CC + c0 + 1) * PP);
    const int4*   m4 = (const int4*)(sm + (size_t)b * PP);

    float a0[KK], a1[KK];
#pragma unroll
    for (int k = 0; k < KK; ++k) { a0[k] = 0.f; a1[k] = 0.f; }

    for (int it = 0; it < PP / 256; ++it) {
        int p = it * 64 + lane;
        int4   mv = m4[p];
        float4 v0 = f0[p];
        float4 v1 = f1[p];

        auto px = [&](int m_, float x0, float x1) {
#pragma unroll
            for (int k = 0; k < KK; ++k) {
                float pr = (m_ == k + 1) ? 1.0f : 0.0f;
                a0[k] = fmaf(pr, x0, a0[k]);
                a1[k] = fmaf(pr, x1, a1[k]);
            }
        };
        px(mv.x, v0.x, v1.x);
        px(mv.y, v0.y, v1.y);
        px(mv.z, v0.z, v1.z);
        px(mv.w, v0.w, v1.w);
    }

#pragma unroll
    for (int k = 0; k < KK; ++k) {
#pragma unroll
        for (int s = 32; s >= 1; s >>= 1) {
            a0[k] += __shfl_xor(a0[k], s, 64);
            a1[k] += __shfl_xor(a1[k], s, 64);
        }
    }

    if (lane == 0) {
        // num[b][k][c]
        float* o = num + (size_t)b * KK * CC + c0;
#pragma unroll
        for (int k = 0; k < KK; ++k) {
            o[(size_t)k * CC]     = a0[k];
            o[(size_t)k * CC + 1] = a1[k];
        }
    }
}

// ---- kernel 2: per-(b,k) denominator + prototype + norm ----
// grid 128 = B(8) x K(16); block 256. Phase 1 counts the mask for class k
// (128 KiB mask is L2-hot after k_num). Phase 2: float4-coalesced read of
// num[b][k][:], IEEE div, transposed write to proto_t[b][c][k], norm reduce.
__global__ __launch_bounds__(256) void k_proto(const float* __restrict__ num,
                                               const int* __restrict__ sm,
                                               float* __restrict__ proto_t,
                                               float* __restrict__ pn) {
    int b    = blockIdx.x >> 4;
    int k    = blockIdx.x & 15;
    int tid  = threadIdx.x;
    int lane = tid & 63;
    int wv   = tid >> 6;

    // --- phase 1: den = count(mask == k+1) over 4096 pixels (exact: ints < 2^24)
    const int4* m4 = (const int4*)(sm + (size_t)b * PP);
    float cnt = 0.f;
#pragma unroll
    for (int i = 0; i < 4; ++i) {
        int4 mv = m4[i * 256 + tid];
        cnt += (mv.x == k + 1) ? 1.f : 0.f;
        cnt += (mv.y == k + 1) ? 1.f : 0.f;
        cnt += (mv.z == k + 1) ? 1.f : 0.f;
        cnt += (mv.w == k + 1) ? 1.f : 0.f;
    }
#pragma unroll
    for (int s = 32; s >= 1; s >>= 1) cnt += __shfl_xor(cnt, s, 64);

    __shared__ float cred[4];
    __shared__ float den_s;
    if (lane == 0) cred[wv] = cnt;
    __syncthreads();
    if (tid == 0) den_s = cred[0] + cred[1] + cred[2] + cred[3];
    __syncthreads();
    float d = den_s;

    // --- phase 2: proto = num/den (elementwise IEEE div, matches numpy), norm
    const float4* nu = (const float4*)(num + (size_t)(b * KK + k) * CC);
    float4 n4 = nu[tid];
    float4 pv;
    pv.x = n4.x / d; pv.y = n4.y / d; pv.z = n4.z / d; pv.w = n4.w / d;

    int c = tid * 4;
    float* pt = proto_t + ((size_t)b * CC + c) * KK + k;
    pt[0]      = pv.x;
    pt[KK]     = pv.y;
    pt[2 * KK] = pv.z;
    pt[3 * KK] = pv.w;

    float sq = pv.x * pv.x;
    sq = fmaf(pv.y, pv.y, sq);
    sq = fmaf(pv.z, pv.z, sq);
    sq = fmaf(pv.w, pv.w, sq);
#pragma unroll
    for (int s = 32; s >= 1; s >>= 1) sq += __shfl_xor(sq, s, 64);

    __shared__ float red[4];
    if (lane == 0) red[wv] = sq;
    __syncthreads();
    if (tid == 0) pn[b * KK + k] = sqrtf(red[0] + red[1] + red[2] + red[3]);
}

// ---- kernel 3: cosine similarity + argmax ----
// grid 256 = B(8) x pgroup(32); block 512 = 8 waves, wave = one 128-channel
// chunk x 128 pixels (float2/lane). Protos via wave-uniform scalar loads.
// Cross-chunk reduce: conflict-free float2 LDS (k-major, b64 ops).
__global__ __launch_bounds__(512) void k_match(const float* __restrict__ qf,
                                               const float* __restrict__ proto_t,
                                               const float* __restrict__ pn,
                                               int* __restrict__ out) {
    int b    = blockIdx.x >> 5;
    int pg   = blockIdx.x & 31;
    int tid  = threadIdx.x;
    int lane = tid & 63;
    int w    = __builtin_amdgcn_readfirstlane(tid >> 6);  // 0..7, wave-uniform
    int c0   = w * 128;
    int px0  = pg * 128;

    const float2* q2 = (const float2*)(qf + ((size_t)b * CC + c0) * PP + px0);
    const float*  pt = proto_t + ((size_t)b * CC + c0) * KK;

    float2 dot[KK];
#pragma unroll
    for (int k = 0; k < KK; ++k) { dot[k].x = 0.f; dot[k].y = 0.f; }
    float2 qs; qs.x = 0.f; qs.y = 0.f;

    for (int ci = 0; ci < 128; ++ci) {
        float2 qv = q2[(size_t)ci * (PP / 2) + lane];
        const float* pr = pt + ci * KK;
#pragma unroll
        for (int k = 0; k < KK; ++k) {
            float p = pr[k];
            dot[k].x = fmaf(p, qv.x, dot[k].x);
            dot[k].y = fmaf(p, qv.y, dot[k].y);
        }
        qs.x = fmaf(qv.x, qv.x, qs.x);
        qs.y = fmaf(qv.y, qv.y, qs.y);
    }

    // buf[c][k][lane] as float2: lane stride 8B -> conflict-free b64 LDS ops
    __shared__ float2 buf[4][KK + 1][64];   // 34.8 KiB

    if (w >= 4) {
#pragma unroll
        for (int k = 0; k < KK; ++k) buf[w - 4][k][lane] = dot[k];
        buf[w - 4][KK][lane] = qs;
    }
    __syncthreads();
    if (w < 4) {
#pragma unroll
        for (int k = 0; k < KK; ++k) {
            float2 t = buf[w][k][lane];
            t.x += dot[k].x; t.y += dot[k].y;
            buf[w][k][lane] = t;
        }
        float2 t = buf[w][KK][lane];
        t.x += qs.x; t.y += qs.y;
        buf[w][KK][lane] = t;
    }
    __syncthreads();

    if (tid < 128) {
        int px = tid;                      // buf[c][k] viewed as float[128]
        const float* bf = (const float*)buf;
        float q2s = 0.f;
#pragma unroll
        for (int c = 0; c < 4; ++c) q2s += bf[((c * (KK + 1)) + KK) * 128 + px];
        float qn = sqrtf(q2s);

        float bv = -INFINITY;
        int   bi = 0;
#pragma unroll
        for (int k = 0; k < KK; ++k) {
            float dk = 0.f;
#pragma unroll
            for (int c = 0; c < 4; ++c) dk += bf[((c * (KK + 1)) + k) * 128 + px];
            float s = dk / fmaxf(pn[b * KK + k] * qn, EPSF);
            if (s > bv) { bv = s; bi = k; }   // strict '>' = first-max (jnp.argmax)
        }
        out[(size_t)b * PP + px0 + px] = bi;
    }
}

extern "C" void kernel_launch(void* const* d_in, const int* in_sizes, int n_in,
                              void* d_out, int out_size, void* d_ws, size_t ws_size,
                              hipStream_t stream) {
    const float* sf = (const float*)d_in[0];  // support_features (8,1024,64,64) f32
    const int*   sm = (const int*)d_in[1];    // support_masks    (8,1,64,64)    i32
    const float* qf = (const float*)d_in[2];  // query_features   (8,1024,64,64) f32
    int* out = (int*)d_out;                   // (8,64,64) i32

    char*  ws      = (char*)d_ws;
    float* num     = (float*)(ws);
    float* pn      = (float*)(ws + (512u << 10));
    float* proto_t = (float*)(ws + (1u << 20));

    hipLaunchKernelGGL(k_num,   dim3(1024), dim3(256), 0, stream, sf, sm, num);
    hipLaunchKernelGGL(k_proto, dim3(128),  dim3(256), 0, stream, num, sm, proto_t, pn);
    hipLaunchKernelGGL(k_match, dim3(256),  dim3(512), 0, stream, qf, proto_t, pn, out);
}

// Round 4
// 286.776 us; speedup vs baseline: 1.1189x; 1.0413x over previous
//
#include <hip/hip_runtime.h>
#include <math.h>

#define BB 8
#define CC 1024
#define PP 4096   // H*W = 64*64
#define KK 16
#define EPSF 1e-8f

// ws layout:
//   num     [B][K][C]  @ 0          (512 KiB)   (c-contiguous)
//   pn      [B][K]     @ 0x80000    (512 B)
//   proto_t [B][C][K]  @ 0x100000   (512 KiB)   (k-contiguous for k_match)

// ---- kernel 1: masked per-class channel sums (prototype numerators) ----
// grid 1024 = B(8) x cgroup(128); block 256 = 4 waves; wave handles 2 channels,
// lanes cover pixels via float4/int4 (1 KiB per wave-load). 4 blocks/CU.
__global__ __launch_bounds__(256) void k_num(const float* __restrict__ sf,
                                             const int* __restrict__ sm,
                                             float* __restrict__ num) {
    int b    = blockIdx.x >> 7;
    int cg   = blockIdx.x & 127;
    int w    = threadIdx.x >> 6;
    int lane = threadIdx.x & 63;
    int c0   = cg * 8 + w * 2;

    const float4* f0 = (const float4*)(sf + ((size_t)b * CC + c0) * PP);
    const float4* f1 = (const float4*)(sf + ((size_t)b * CC + c0 + 1) * PP);
    const int4*   m4 = (const int4*)(sm + (size_t)b * PP);

    float a0[KK], a1[KK];
#pragma unroll
    for (int k = 0; k < KK; ++k) { a0[k] = 0.f; a1[k] = 0.f; }

    for (int it = 0; it < PP / 256; ++it) {
        int p = it * 64 + lane;
        int4   mv = m4[p];
        float4 v0 = f0[p];
        float4 v1 = f1[p];

        auto px = [&](int m_, float x0, float x1) {
#pragma unroll
            for (int k = 0; k < KK; ++k) {
                float pr = (m_ == k + 1) ? 1.0f : 0.0f;
                a0[k] = fmaf(pr, x0, a0[k]);
                a1[k] = fmaf(pr, x1, a1[k]);
            }
        };
        px(mv.x, v0.x, v1.x);
        px(mv.y, v0.y, v1.y);
        px(mv.z, v0.z, v1.z);
        px(mv.w, v0.w, v1.w);
    }

#pragma unroll
    for (int k = 0; k < KK; ++k) {
#pragma unroll
        for (int s = 32; s >= 1; s >>= 1) {
            a0[k] += __shfl_xor(a0[k], s, 64);
            a1[k] += __shfl_xor(a1[k], s, 64);
        }
    }

    if (lane == 0) {
        // num[b][k][c]
        float* o = num + (size_t)b * KK * CC + c0;
#pragma unroll
        for (int k = 0; k < KK; ++k) {
            o[(size_t)k * CC]     = a0[k];
            o[(size_t)k * CC + 1] = a1[k];
        }
    }
}

// ---- kernel 2: per-(b,k) denominator + prototype + norm ----
// grid 128 = B(8) x K(16); block 256. Phase 1 counts the mask for class k
// (128 KiB mask is L2-hot after k_num). Phase 2: float4-coalesced read of
// num[b][k][:], IEEE div, transposed write to proto_t[b][c][k], norm reduce.
__global__ __launch_bounds__(256) void k_proto(const float* __restrict__ num,
                                               const int* __restrict__ sm,
                                               float* __restrict__ proto_t,
                                               float* __restrict__ pn) {
    int b    = blockIdx.x >> 4;
    int k    = blockIdx.x & 15;
    int tid  = threadIdx.x;
    int lane = tid & 63;
    int wv   = tid >> 6;

    // --- phase 1: den = count(mask == k+1) over 4096 pixels (exact: ints < 2^24)
    const int4* m4 = (const int4*)(sm + (size_t)b * PP);
    float cnt = 0.f;
#pragma unroll
    for (int i = 0; i < 4; ++i) {
        int4 mv = m4[i * 256 + tid];
        cnt += (mv.x == k + 1) ? 1.f : 0.f;
        cnt += (mv.y == k + 1) ? 1.f : 0.f;
        cnt += (mv.z == k + 1) ? 1.f : 0.f;
        cnt += (mv.w == k + 1) ? 1.f : 0.f;
    }
#pragma unroll
    for (int s = 32; s >= 1; s >>= 1) cnt += __shfl_xor(cnt, s, 64);

    __shared__ float cred[4];
    __shared__ float den_s;
    if (lane == 0) cred[wv] = cnt;
    __syncthreads();
    if (tid == 0) den_s = cred[0] + cred[1] + cred[2] + cred[3];
    __syncthreads();
    float d = den_s;

    // --- phase 2: proto = num/den (elementwise IEEE div, matches numpy), norm
    const float4* nu = (const float4*)(num + (size_t)(b * KK + k) * CC);
    float4 n4 = nu[tid];
    float4 pv;
    pv.x = n4.x / d; pv.y = n4.y / d; pv.z = n4.z / d; pv.w = n4.w / d;

    int c = tid * 4;
    float* pt = proto_t + ((size_t)b * CC + c) * KK + k;
    pt[0]      = pv.x;
    pt[KK]     = pv.y;
    pt[2 * KK] = pv.z;
    pt[3 * KK] = pv.w;

    float sq = pv.x * pv.x;
    sq = fmaf(pv.y, pv.y, sq);
    sq = fmaf(pv.z, pv.z, sq);
    sq = fmaf(pv.w, pv.w, sq);
#pragma unroll
    for (int s = 32; s >= 1; s >>= 1) sq += __shfl_xor(sq, s, 64);

    __shared__ float red[4];
    if (lane == 0) red[wv] = sq;
    __syncthreads();
    if (tid == 0) pn[b * KK + k] = sqrtf(red[0] + red[1] + red[2] + red[3]);
}

// ---- kernel 3: cosine similarity + argmax ----
// grid 512 = B(8) x pgroup(64) of 64 pixels; block 512 = 8 waves, wave = one
// 128-channel chunk x 64 pixels (float/lane) -> 2 blocks/CU, 16 waves/CU.
// ci-loop grouped x4: 4 q-loads in flight per wave (structural ILP).
// Protos via wave-uniform scalar loads; conflict-free LDS reduce.
__global__ __launch_bounds__(512) void k_match(const float* __restrict__ qf,
                                               const float* __restrict__ proto_t,
                                               const float* __restrict__ pn,
                                               int* __restrict__ out) {
    int b    = blockIdx.x >> 6;
    int pg   = blockIdx.x & 63;
    int tid  = threadIdx.x;
    int lane = tid & 63;
    int w    = __builtin_amdgcn_readfirstlane(tid >> 6);  // 0..7, wave-uniform
    int c0   = w * 128;
    int px0  = pg * 64;

    const float* q  = qf + ((size_t)b * CC + c0) * PP + px0 + lane;
    const float* pt = proto_t + ((size_t)b * CC + c0) * KK;

    float dot[KK];
#pragma unroll
    for (int k = 0; k < KK; ++k) dot[k] = 0.f;
    float qs = 0.f;

    for (int ci = 0; ci < 128; ci += 4) {
        // all 4 loads issued before first use -> vmcnt(3..0) pipeline
        float v0 = q[(size_t)(ci + 0) * PP];
        float v1 = q[(size_t)(ci + 1) * PP];
        float v2 = q[(size_t)(ci + 2) * PP];
        float v3 = q[(size_t)(ci + 3) * PP];
        const float* pr = pt + ci * KK;
#pragma unroll
        for (int k = 0; k < KK; ++k)
            dot[k] = fmaf(pr[k], v0, dot[k]);
#pragma unroll
        for (int k = 0; k < KK; ++k)
            dot[k] = fmaf(pr[KK + k], v1, dot[k]);
#pragma unroll
        for (int k = 0; k < KK; ++k)
            dot[k] = fmaf(pr[2 * KK + k], v2, dot[k]);
#pragma unroll
        for (int k = 0; k < KK; ++k)
            dot[k] = fmaf(pr[3 * KK + k], v3, dot[k]);
        qs = fmaf(v0, v0, qs);
        qs = fmaf(v1, v1, qs);
        qs = fmaf(v2, v2, qs);
        qs = fmaf(v3, v3, qs);
    }

    // buf[c][k][lane]: lane stride 4 B -> 2-way bank aliasing (free on CDNA4)
    __shared__ float buf[4][KK + 1][64];   // 17.4 KiB

    if (w >= 4) {
#pragma unroll
        for (int k = 0; k < KK; ++k) buf[w - 4][k][lane] = dot[k];
        buf[w - 4][KK][lane] = qs;
    }
    __syncthreads();
    if (w < 4) {
#pragma unroll
        for (int k = 0; k < KK; ++k) buf[w][k][lane] += dot[k];
        buf[w][KK][lane] += qs;
    }
    __syncthreads();

    if (tid < 64) {
        int px = tid;
        float q2s = 0.f;
#pragma unroll
        for (int c = 0; c < 4; ++c) q2s += buf[c][KK][px];
        float qn = sqrtf(q2s);

        float bv = -INFINITY;
        int   bi = 0;
#pragma unroll
        for (int k = 0; k < KK; ++k) {
            float dk = 0.f;
#pragma unroll
            for (int c = 0; c < 4; ++c) dk += buf[c][k][px];
            float s = dk / fmaxf(pn[b * KK + k] * qn, EPSF);
            if (s > bv) { bv = s; bi = k; }   // strict '>' = first-max (jnp.argmax)
        }
        out[(size_t)b * PP + px0 + px] = bi;
    }
}

extern "C" void kernel_launch(void* const* d_in, const int* in_sizes, int n_in,
                              void* d_out, int out_size, void* d_ws, size_t ws_size,
                              hipStream_t stream) {
    const float* sf = (const float*)d_in[0];  // support_features (8,1024,64,64) f32
    const int*   sm = (const int*)d_in[1];    // support_masks    (8,1,64,64)    i32
    const float* qf = (const float*)d_in[2];  // query_features   (8,1024,64,64) f32
    int* out = (int*)d_out;                   // (8,64,64) i32

    char*  ws      = (char*)d_ws;
    float* num     = (float*)(ws);
    float* pn      = (float*)(ws + (512u << 10));
    float* proto_t = (float*)(ws + (1u << 20));

    hipLaunchKernelGGL(k_num,   dim3(1024), dim3(256), 0, stream, sf, sm, num);
    hipLaunchKernelGGL(k_proto, dim3(128),  dim3(256), 0, stream, num, sm, proto_t, pn);
    hipLaunchKernelGGL(k_match, dim3(512),  dim3(512), 0, stream, qf, proto_t, pn, out);
}